// Round 7
// baseline (154.281 us; speedup 1.0000x reference)
//
#include <hip/hip_runtime.h>
#include <hip/hip_bf16.h>

#define HID   64
#define BLOCK 256
#define GPW   4      // tiles of 16 tokens per wave; block = 4 waves * 64 tok = 256 tokens

typedef short short8 __attribute__((ext_vector_type(8)));
typedef float floatx4 __attribute__((ext_vector_type(4)));

// two float4 -> bf16 short8 via packed RNE cvt
__device__ __forceinline__ short8 cvt8f(float4 f0, float4 f1) {
    union { __hip_bfloat162 h[4]; short8 s; } r;
    r.h[0] = __float22bfloat162_rn(make_float2(f0.x, f0.y));
    r.h[1] = __float22bfloat162_rn(make_float2(f0.z, f0.w));
    r.h[2] = __float22bfloat162_rn(make_float2(f1.x, f1.y));
    r.h[3] = __float22bfloat162_rn(make_float2(f1.z, f1.w));
    return r.s;
}

__device__ __forceinline__ void gload_lds16(const float* g, float* l) {
    __builtin_amdgcn_global_load_lds(
        (const __attribute__((address_space(1))) void*)g,
        (__attribute__((address_space(3))) void*)l, 16, 0, 0);
}

#define SB __builtin_amdgcn_sched_barrier(0)

// Stage tile g (16 tokens, 4 KB) into this wave's buffer g. Consumption-order
// layout (rule 21: pre-swizzled GLOBAL src, linear LDS dest): chunk c=kc*2+hf,
// slot (c,lane) = x[tok0 + g*16 + r15][kg*8 + kc*32 + hf*4 .. +4)
#define STAGE(g) do {                                                             \
    _Pragma("unroll")                                                             \
    for (int c = 0; c < 4; ++c) {                                                 \
        const int kc_ = c >> 1, hf_ = c & 1;                                      \
        const float* src_ = x + (tok0 + (g) * 16 + r15) * (long)HID               \
                              + kg * 8 + kc_ * 32 + hf_ * 4;                      \
        gload_lds16(src_, &sbuf[wave][(g)][c * 256]);                             \
    } } while (0)

// Compute tile g from its buffer: 16 tokens x 64 cols, 3 modalities, select.
#define COMPUTE(g) do {                                                           \
    const float4 q0 = *(const float4*)&sbuf[wave][(g)][0 * 256 + lane * 4];       \
    const float4 q1 = *(const float4*)&sbuf[wave][(g)][1 * 256 + lane * 4];       \
    const float4 q2 = *(const float4*)&sbuf[wave][(g)][2 * 256 + lane * 4];       \
    const float4 q3 = *(const float4*)&sbuf[wave][(g)][3 * 256 + lane * 4];       \
    const short8 xb0 = cvt8f(q0, q1);                                             \
    const short8 xb1 = cvt8f(q2, q3);                                             \
    const int m_ = mreg[(g)];                                                     \
    float* ob_ = out + (tok0 + (g) * 16 + r15) * (long)HID + kg * 4;              \
    _Pragma("unroll")                                                             \
    for (int nt = 0; nt < 4; ++nt) {                                              \
        floatx4 a0 = {0.f,0.f,0.f,0.f}, a1 = {0.f,0.f,0.f,0.f},                   \
                a2 = {0.f,0.f,0.f,0.f};                                           \
        a0 = __builtin_amdgcn_mfma_f32_16x16x32_bf16(wa[0][nt][0], xb0, a0,0,0,0);\
        a0 = __builtin_amdgcn_mfma_f32_16x16x32_bf16(wa[0][nt][1], xb1, a0,0,0,0);\
        a1 = __builtin_amdgcn_mfma_f32_16x16x32_bf16(wa[1][nt][0], xb0, a1,0,0,0);\
        a1 = __builtin_amdgcn_mfma_f32_16x16x32_bf16(wa[1][nt][1], xb1, a1,0,0,0);\
        a2 = __builtin_amdgcn_mfma_f32_16x16x32_bf16(wa[2][nt][0], xb0, a2,0,0,0);\
        a2 = __builtin_amdgcn_mfma_f32_16x16x32_bf16(wa[2][nt][1], xb1, a2,0,0,0);\
        const floatx4 v_ = (m_ == 0) ? a0 : ((m_ == 1) ? a1 : a2);                \
        *(floatx4*)(ob_ + nt * 16) = v_;                                          \
    } } while (0)

// Constant counted wait: before COMPUTE(g), younger VMEM = 4*(3-g) remaining
// stage loads + 4*g own stores = 12. Stores are youngest -> never gate.
#define WAIT12 asm volatile("s_waitcnt vmcnt(12)" ::: "memory")

__global__ __launch_bounds__(BLOCK) void moe_burst(
    const float* __restrict__ x,
    const float* __restrict__ W,
    const int* __restrict__ mod,
    float* __restrict__ out)
{
    __shared__ float sbuf[4][GPW][1024];   // [wave][tile][16 tok * 64 f] = 64 KB

    const int tid  = threadIdx.x;
    const int wave = tid >> 6;
    const int lane = tid & 63;
    const int r15  = lane & 15;            // token index within tile
    const int kg   = lane >> 4;            // k-group 0..3

    const long tok0 = (long)blockIdx.x * (64 * GPW) + wave * (16 * GPW);

    // ---- prologue A: mod loads, pinned (forces completion -> drained) ----
    int mreg[GPW];
#pragma unroll
    for (int g = 0; g < GPW; ++g)
        mreg[g] = mod[tok0 + g * 16 + r15];
    asm volatile("" :: "v"(mreg[0]), "v"(mreg[1]), "v"(mreg[2]), "v"(mreg[3]));

    // ---- prologue B: W fragments (loads consumed by cvt -> drained) ----
    short8 wa[3][4][2];
#pragma unroll
    for (int mm = 0; mm < 3; ++mm)
#pragma unroll
        for (int nt = 0; nt < 4; ++nt) {
            const float* wp = W + mm * 4096 + (nt * 16 + r15) * HID + kg * 8;
            wa[mm][nt][0] = cvt8f(*(const float4*)wp,        *(const float4*)(wp + 4));
            wa[mm][nt][1] = cvt8f(*(const float4*)(wp + 32), *(const float4*)(wp + 36));
        }
    SB;

    // ---- burst: ALL 16 stage loads in flight at once (16 KB/wave) ----
    STAGE(0); STAGE(1); STAGE(2); STAGE(3); SB;

    // ---- drain tiles with constant counted vmcnt; no barriers anywhere ----
    WAIT12; SB; COMPUTE(0); SB;
    WAIT12; SB; COMPUTE(1); SB;
    WAIT12; SB; COMPUTE(2); SB;
    WAIT12; SB; COMPUTE(3);
}

extern "C" void kernel_launch(void* const* d_in, const int* in_sizes, int n_in,
                              void* d_out, int out_size, void* d_ws, size_t ws_size,
                              hipStream_t stream) {
    const float* x   = (const float*)d_in[0];
    const float* W   = (const float*)d_in[1];
    const int*   mod = (const int*)d_in[2];
    float*       out = (float*)d_out;

    const int n      = in_sizes[0] / HID;     // tokens (1<<20)
    const int blocks = n / (64 * GPW);        // 4096

    moe_burst<<<blocks, BLOCK, 0, stream>>>(x, W, mod, out);
}